// Round 8
// baseline (426.904 us; speedup 1.0000x reference)
//
#include <hip/hip_runtime.h>
#include <hip/hip_bf16.h>

#define BSZ 4096
#define MAXLEN 200
#define EDIM 112
#define NPL 8      // K-split partial planes (one per kq block-group)
#define NBLK 256   // mega grid; == #CUs -> co-resident, manual grid sync safe

typedef __attribute__((ext_vector_type(8))) short bf16x8;
typedef __attribute__((ext_vector_type(4))) float f32x4;

// f32 -> bf16 (RNE), bit-level
static __device__ __forceinline__ short f2bf(float f) {
    unsigned u = __float_as_uint(f);
    unsigned r = (u + 0x7fffu + ((u >> 16) & 1u)) >> 16;
    return (short)r;
}
static __device__ __forceinline__ float bf2f(short s) {
    return __uint_as_float(((unsigned)(unsigned short)s) << 16);
}
static __device__ __forceinline__ bf16x8 cvt8(float4 a, float4 b) {
    bf16x8 r;
    r[0] = f2bf(a.x); r[1] = f2bf(a.y); r[2] = f2bf(a.z); r[3] = f2bf(a.w);
    r[4] = f2bf(b.x); r[5] = f2bf(b.y); r[6] = f2bf(b.z); r[7] = f2bf(b.w);
    return r;
}
static __device__ __forceinline__ unsigned pack2(float a, float b) {
    return ((unsigned)f2bf(a) & 0xffffu) | ((unsigned)f2bf(b) << 16);
}

// async global->LDS, 16 B per lane: global src per-lane, LDS dest uniform+lane*16.
static __device__ __forceinline__ void glds16(const unsigned short* g, unsigned short* l) {
    __builtin_amdgcn_global_load_lds(
        (__attribute__((address_space(1))) void*)(void*)g,
        (__attribute__((address_space(3))) void*)l, 16, 0, 0);
}

// Monotonic grid barrier: every block adds 1 per sync; sync #idx releases when
// cnt >= idx*NBLK (each block adds exactly once per sync, in order, so cnt
// reaches idx*NBLK only when ALL blocks arrived).  cnt zeroed by hipMemsetAsync
// before launch (graph-legal).  Safe: 256 blocks x 1 block/CU on 256 CUs are
// always co-resident.
static __device__ __forceinline__ void gsync(unsigned* cnt, unsigned idx) {
    __syncthreads();
    if (threadIdx.x == 0) {
        __threadfence();   // release: block's global stores -> device visible
        __hip_atomic_fetch_add(cnt, 1u, __ATOMIC_RELEASE, __HIP_MEMORY_SCOPE_AGENT);
        while (__hip_atomic_load(cnt, __ATOMIC_ACQUIRE, __HIP_MEMORY_SCOPE_AGENT)
               < idx * (unsigned)NBLK)
            __builtin_amdgcn_s_sleep(2);
        __threadfence();   // acquire: invalidate stale cached lines
    }
    __syncthreads();
}

// Streaming f32 -> bf16; first `zgroups` 8-elem groups are zeros (PAD row).
__global__ __launch_bounds__(256) void f32_to_bf16(const float* __restrict__ src,
                                                   unsigned short* __restrict__ dst,
                                                   int ngroups, int zgroups) {
    int g = blockIdx.x * 256 + threadIdx.x;
    if (g >= ngroups) return;
    bf16x8 o;
    if (g < zgroups) {
        #pragma unroll
        for (int i = 0; i < 8; ++i) o[i] = 0;
    } else {
        const float* p = src + (size_t)(g - zgroups) * 8;
        float4 a = *(const float4*)p;
        float4 b = *(const float4*)(p + 4);
        o = cvt8(a, b);
    }
    *(bf16x8*)(dst + (size_t)g * 8) = o;
}

// bf16-table gather+mean-pool. One block per session; 4 waves x 4 rows/wave,
// 16 B/lane loads; Ebf row 0 is zeros (PAD).  Writes S and inits acc.
__global__ __launch_bounds__(256) void gather_pool_bf(const unsigned short* __restrict__ Ebf,
                                                      const int* __restrict__ items,
                                                      const float* __restrict__ slen,
                                                      float* __restrict__ S,
                                                      float* __restrict__ acc) {
    __shared__ float part[16][14][8];
    int wave = threadIdx.x >> 6;
    int lane = threadIdx.x & 63;
    int b = blockIdx.x;
    int rg = lane / 14;   // 0..3 for lanes 0..55
    int c  = lane % 14;
    const int* it = items + (size_t)b * MAXLEN + wave * 50;
    float a[8];
    #pragma unroll
    for (int e = 0; e < 8; ++e) a[e] = 0.f;
    if (lane < 56) {
        #pragma unroll
        for (int t = 0; t < 13; ++t) {
            int j = t * 4 + rg;
            int idx = 0;
            if (j < 50) idx = it[j];               // idx==0 -> zero row (PAD)
            bf16x8 v = *(const bf16x8*)(Ebf + (size_t)idx * EDIM + c * 8);
            #pragma unroll
            for (int e = 0; e < 8; ++e) a[e] += bf2f(v[e]);
        }
        #pragma unroll
        for (int e = 0; e < 8; ++e) part[wave * 4 + rg][c][e] = a[e];
    }
    __syncthreads();
    int tid = threadIdx.x;
    if (tid < EDIM) {
        int cc = tid >> 3, ee = tid & 7;
        float s = 0.f;
        #pragma unroll
        for (int g = 0; g < 16; ++g) s += part[g][cc][ee];
        s /= slen[b];
        S[(size_t)b * EDIM + tid]   = s;
        acc[(size_t)b * EDIM + tid] = s;
    }
}

// Load 8 consecutive f32 (if valid) -> bf16x8 fragment.
static __device__ __forceinline__ bf16x8 ldcvt(const float* p, bool valid) {
    if (valid) {
        float4 a = *(const float4*)(p);
        float4 b = *(const float4*)(p + 4);
        return cvt8(a, b);
    }
    bf16x8 z;
    #pragma unroll
    for (int i = 0; i < 8; ++i) z[i] = 0;
    return z;
}

// ONE kernel for mid0 + 3 x (K-split GEMM + epilogue) + final.
// grid 256 x 512 (1 block/CU at 56 KB LDS).  6 grid syncs replace 5 kernel
// boundaries.
//
// mid0  : wave 0 of block b computes T1 tile for sessions [16b,16b+16) -> Bsw0.
// bg(l) : block b = (mtile=b&31, kq=b>>5): rows [128*mtile,+128), K-chunk
//         [512*kq,+512).  B slice staged to LDS in two 56-KB phases (8 k32 x
//         7 frags each); 16 A-frags prefetched to regs (l==0: f32+cvt+side-
//         write Asw).  112 MFMA/wave, no global loads/barriers in compute.
//         Partial 128x112 tile -> Yp plane kq.
// epi(l): block b owns sessions [16b,16b+16): all 512 thr reduce the 8 Yp
//         planes into LDS, wave 0 does D-scale, L2-norm, acc/out update and
//         (l<2) T' = Y @ W^T -> Bsw for the next layer.
__global__ __launch_bounds__(512, 2) void mega(const float* __restrict__ Af,
                                               unsigned short* __restrict__ Asw,
                                               const float* __restrict__ Sin,
                                               const float* __restrict__ Dm,
                                               float* __restrict__ accb,
                                               const float* __restrict__ Ws,
                                               unsigned short* __restrict__ Bsw0,
                                               unsigned short* __restrict__ Bsw1,
                                               float* __restrict__ Yp,
                                               float* __restrict__ out,
                                               unsigned* __restrict__ cnt) {
    // bg phase needs 8*7*512 shorts = 57,344 B (round-7 bug: was 28,672 B ->
    // global_load_lds ran past the LDS allocation -> GPU fault).
    __shared__ alignas(16) char smem[57344];
    int tid = threadIdx.x;
    int w = tid >> 6;
    int lane = tid & 63;
    int nrow = lane & 15;
    int quad = lane >> 4;
    int b = blockIdx.x;

    // ================= phase M0: T1 = S @ W0^T (wave 0) =================
    if (w == 0) {
        unsigned short (*Ylds)[136] = (unsigned short(*)[136])smem;
        int j0 = b * 16;
        int ses = j0 + nrow;
        float4 v[7];
        const float4* p = (const float4*)(Sin + (size_t)ses * EDIM + quad * 28);
        #pragma unroll
        for (int i = 0; i < 7; ++i) v[i] = p[i];
        #pragma unroll
        for (int i = 0; i < 7; ++i) {
            uint2 pk;
            pk.x = pack2(v[i].x, v[i].y);
            pk.y = pack2(v[i].z, v[i].w);
            *(uint2*)&Ylds[nrow][quad * 28 + i * 4] = pk;
        }
        *(uint2*)&Ylds[nrow][112 + quad * 4] = make_uint2(0u, 0u);
        __builtin_amdgcn_s_waitcnt(0);  // drain ds_write before ds_read (same wave)
        bf16x8 aF[4];
        #pragma unroll
        for (int k = 0; k < 4; ++k)
            aF[k] = *(bf16x8*)&Ylds[nrow][k * 32 + quad * 8];
        f32x4 acc[7];
        #pragma unroll
        for (int t = 0; t < 7; ++t) acc[t] = (f32x4){0.f, 0.f, 0.f, 0.f};
        #pragma unroll
        for (int t = 0; t < 7; ++t) {
            const float* wr = Ws + (size_t)(16 * t + nrow) * EDIM;
            #pragma unroll
            for (int k = 0; k < 4; ++k) {
                bf16x8 bF = ldcvt(wr + k * 32 + quad * 8, (k < 3) || (quad < 2));
                acc[t] = __builtin_amdgcn_mfma_f32_16x16x32_bf16(aF[k], bF, acc[t], 0, 0, 0);
            }
        }
        int k32f = j0 >> 5;
        int qp = ((j0 >> 4) & 1) * 2 + (quad >> 1);
        int e0 = (quad & 1) * 4;
        #pragma unroll
        for (int t = 0; t < 7; ++t) {
            uint2 pk;
            pk.x = pack2(acc[t][0], acc[t][1]);
            pk.y = pack2(acc[t][2], acc[t][3]);
            *(uint2*)(Bsw0 + ((size_t)(k32f * 7 + t) * 64 + qp * 16 + nrow) * 8 + e0) = pk;
        }
    }
    gsync(cnt, 1);

    // ================= three layers =================
    #pragma unroll 1
    for (int l = 0; l < 3; ++l) {
        // ---------- bg: partial GEMM ----------
        {
            unsigned short* Bl = (unsigned short*)smem;   // 8 k32 x 7 frags = 57,344 B
            const unsigned short* BswIn = (l == 1) ? Bsw1 : Bsw0;
            int mtile = b & 31;
            int kq = b >> 5;
            int M16 = mtile * 8 + w;
            int k32b = kq * 16;

            #pragma unroll
            for (int t = 0; t < 7; ++t)
                glds16(BswIn + (((size_t)(k32b + w) * 7 + t) * 64 + lane) * 8,
                       &Bl[(w * 7 + t) * 512]);

            bf16x8 aF[16];
            if (l == 0) {
                #pragma unroll
                for (int k = 0; k < 16; ++k) {
                    const float* p = Af + (size_t)(M16 * 16 + nrow) * BSZ
                                     + (k32b + k) * 32 + quad * 8;
                    float4 a0 = *(const float4*)p;
                    float4 a1 = *(const float4*)(p + 4);
                    aF[k] = cvt8(a0, a1);
                    *(bf16x8*)(Asw + (((size_t)M16 * 128 + k32b + k) * 64 + lane) * 8) = aF[k];
                }
            } else {
                #pragma unroll
                for (int k = 0; k < 16; ++k)
                    aF[k] = *(const bf16x8*)(Asw + (((size_t)M16 * 128 + k32b + k) * 64 + lane) * 8);
            }

            f32x4 acc[7];
            #pragma unroll
            for (int t = 0; t < 7; ++t) acc[t] = (f32x4){0.f, 0.f, 0.f, 0.f};

            asm volatile("s_waitcnt vmcnt(0)" ::: "memory");
            __syncthreads();
            #pragma unroll
            for (int k = 0; k < 8; ++k)
                #pragma unroll
                for (int t = 0; t < 7; ++t) {
                    bf16x8 bF = *(bf16x8*)&Bl[(k * 7 + t) * 512 + lane * 8];
                    acc[t] = __builtin_amdgcn_mfma_f32_16x16x32_bf16(aF[k], bF, acc[t], 0, 0, 0);
                }
            __syncthreads();
            #pragma unroll
            for (int t = 0; t < 7; ++t)
                glds16(BswIn + (((size_t)(k32b + 8 + w) * 7 + t) * 64 + lane) * 8,
                       &Bl[(w * 7 + t) * 512]);
            asm volatile("s_waitcnt vmcnt(0)" ::: "memory");
            __syncthreads();
            #pragma unroll
            for (int k = 0; k < 8; ++k)
                #pragma unroll
                for (int t = 0; t < 7; ++t) {
                    bf16x8 bF = *(bf16x8*)&Bl[(k * 7 + t) * 512 + lane * 8];
                    acc[t] = __builtin_amdgcn_mfma_f32_16x16x32_bf16(aF[8 + k], bF, acc[t], 0, 0, 0);
                }

            float* dst = Yp + (size_t)kq * BSZ * EDIM + (size_t)M16 * 16 * EDIM;
            #pragma unroll
            for (int t = 0; t < 7; ++t)
                #pragma unroll
                for (int r = 0; r < 4; ++r)
                    dst[(size_t)(quad * 4 + r) * EDIM + 16 * t + nrow] = acc[t][r];
        }
        gsync(cnt, 2 + 2 * l);

        // ---------- epi: reduce planes + norm + acc/out + T' ----------
        {
            float4* Yred = (float4*)smem;                              // 7,168 B
            unsigned short (*Ylds)[136] = (unsigned short(*)[136])(smem + 7168);
            if (tid < 448) {
                int row = tid / 28;
                int c4 = tid - row * 28;
                float4 s = make_float4(0.f, 0.f, 0.f, 0.f);
                #pragma unroll
                for (int pp = 0; pp < NPL; ++pp) {
                    float4 t = *(const float4*)(Yp + (size_t)pp * BSZ * EDIM
                                                + (size_t)(b * 16 + row) * EDIM + c4 * 4);
                    s.x += t.x; s.y += t.y; s.z += t.z; s.w += t.w;
                }
                Yred[row * 28 + c4] = s;
            }
            __syncthreads();
            if (w == 0) {
                float4 v[7];
                #pragma unroll
                for (int i = 0; i < 7; ++i) v[i] = Yred[nrow * 28 + quad * 7 + i];
                float d = Dm[(size_t)(b * 16 + nrow) * (BSZ + 1)];
                float ss = 0.f;
                #pragma unroll
                for (int i = 0; i < 7; ++i) {
                    v[i].x *= d; v[i].y *= d; v[i].z *= d; v[i].w *= d;
                    ss += v[i].x * v[i].x + v[i].y * v[i].y
                        + v[i].z * v[i].z + v[i].w * v[i].w;
                }
                ss += __shfl_xor(ss, 16, 64);
                ss += __shfl_xor(ss, 32, 64);
                float rinv = 1.f / fmaxf(sqrtf(ss), 1e-12f);
                if (l == 2) {
                    #pragma unroll
                    for (int i = 0; i < 7; ++i) {
                        size_t o = (size_t)(b * 16 + nrow) * EDIM + quad * 28 + i * 4;
                        float4 a = *(const float4*)(accb + o);
                        float4 r;
                        r.x = (a.x + v[i].x * rinv) * 0.25f;
                        r.y = (a.y + v[i].y * rinv) * 0.25f;
                        r.z = (a.z + v[i].z * rinv) * 0.25f;
                        r.w = (a.w + v[i].w * rinv) * 0.25f;
                        *(float4*)(out + o) = r;
                    }
                } else {
                    #pragma unroll
                    for (int i = 0; i < 7; ++i) {
                        size_t o = (size_t)(b * 16 + nrow) * EDIM + quad * 28 + i * 4;
                        float4 a = *(const float4*)(accb + o);
                        a.x += v[i].x * rinv; a.y += v[i].y * rinv;
                        a.z += v[i].z * rinv; a.w += v[i].w * rinv;
                        *(float4*)(accb + o) = a;
                        uint2 pk;
                        pk.x = pack2(v[i].x, v[i].y);
                        pk.y = pack2(v[i].z, v[i].w);
                        *(uint2*)&Ylds[nrow][quad * 28 + i * 4] = pk;
                    }
                    *(uint2*)&Ylds[nrow][112 + quad * 4] = make_uint2(0u, 0u);
                    __builtin_amdgcn_s_waitcnt(0);
                    bf16x8 aF2[4];
                    #pragma unroll
                    for (int k = 0; k < 4; ++k)
                        aF2[k] = *(bf16x8*)&Ylds[nrow][k * 32 + quad * 8];
                    const float* Wn = Ws + (size_t)(l + 1) * EDIM * EDIM;
                    unsigned short* BswOut = (l == 0) ? Bsw1 : Bsw0;
                    int j0 = b * 16;
                    int k32f = j0 >> 5;
                    int qp = ((j0 >> 4) & 1) * 2 + (quad >> 1);
                    int e0 = (quad & 1) * 4;
                    #pragma unroll
                    for (int t = 0; t < 7; ++t) {
                        f32x4 c = (f32x4){0.f, 0.f, 0.f, 0.f};
                        const float* wr = Wn + (size_t)(16 * t + nrow) * EDIM;
                        #pragma unroll
                        for (int k = 0; k < 4; ++k) {
                            bf16x8 bW = ldcvt(wr + k * 32 + quad * 8, (k < 3) || (quad < 2));
                            c = __builtin_amdgcn_mfma_f32_16x16x32_bf16(aF2[k], bW, c, 0, 0, 0);
                        }
                        uint2 ck;
                        ck.x = pack2(c[0], c[1]);
                        ck.y = pack2(c[2], c[3]);
                        *(uint2*)(BswOut + ((size_t)(k32f * 7 + t) * 64 + qp * 16 + nrow) * 8 + e0) = ck;
                    }
                }
            }
        }
        if (l < 2) gsync(cnt, 3 + 2 * l);
    }
}

extern "C" void kernel_launch(void* const* d_in, const int* in_sizes, int n_in,
                              void* d_out, int out_size, void* d_ws, size_t ws_size,
                              hipStream_t stream) {
    (void)in_sizes; (void)n_in; (void)out_size; (void)ws_size;
    const float* emb   = (const float*)d_in[0];
    const float* Dm    = (const float*)d_in[1];
    const float* A     = (const float*)d_in[2];
    const float* slen  = (const float*)d_in[3];
    const float* Ws    = (const float*)d_in[4];
    const int*   items = (const int*)d_in[5];
    float* out = (float*)d_out;

    // workspace layout (16B-aligned), ~76 MB total
    char* w = (char*)d_ws;
    float* Sa   = (float*)w;                                      // 1835008 B
    float* accb = Sa + BSZ * EDIM;                                // 1835008 B
    float* Yp   = accb + BSZ * EDIM;                              // NPL x 1835008 B
    unsigned short* Bsw0 = (unsigned short*)(Yp + (size_t)NPL * BSZ * EDIM); // 917504 B
    unsigned short* Bsw1 = Bsw0 + (size_t)128 * 7 * 64 * 8;       // 917504 B
    unsigned short* Ebf  = Bsw1 + (size_t)128 * 7 * 64 * 8;       // 22400224 B
    unsigned short* Asw  = Ebf + (size_t)100001 * EDIM;           // 33554432 B
    unsigned* cnt = (unsigned*)(Asw + (size_t)BSZ * BSZ);         // 64 B barrier state

    // 0. zero the grid-barrier counter (graph-legal async memset)
    hipMemsetAsync(cnt, 0, 64, stream);
    // 1. embedding table -> bf16 (zero PAD row prepended)
    f32_to_bf16<<<5470, 256, 0, stream>>>(emb, Ebf, 1400014, 14);
    // 2. gather + mean-pool -> S, acc  (latency-bound: keep full 4096-block grid)
    gather_pool_bf<<<BSZ, 256, 0, stream>>>(Ebf, items, slen, Sa, accb);
    // 3. everything else in ONE kernel (mid0 + 3x(bg+epi) + final)
    mega<<<NBLK, 512, 0, stream>>>(A, Asw, Sa, Dm, accb, Ws,
                                   Bsw0, Bsw1, Yp, out, cnt);
}